// Round 6
// baseline (118.476 us; speedup 1.0000x reference)
//
#include <hip/hip_runtime.h>
#include <hip/hip_bf16.h>
#include <stdint.h>

typedef __bf16 bf16_t;
typedef __bf16 bf16x8 __attribute__((ext_vector_type(8)));
typedef float f32x4 __attribute__((ext_vector_type(4)));

#define NB 2
#define NN 2048
#define ND 1024
#define NH 16
#define DHEAD 64
#define WIN 128

__device__ __forceinline__ void load_lds16(const void* g, void* l) {
  __builtin_amdgcn_global_load_lds(
      (const __attribute__((address_space(1))) uint32_t*)g,
      (__attribute__((address_space(3))) uint32_t*)l, 16, 0, 0);
}

__global__ __launch_bounds__(256) void cast_kernel(const float* __restrict__ in,
                                                   bf16_t* __restrict__ out, int n4) {
  int i = blockIdx.x * 256 + threadIdx.x;
  if (i < n4) {
    float4 v = reinterpret_cast<const float4*>(in)[i];
    union { bf16_t h[4]; uint2 u; } o;
    o.h[0] = (bf16_t)v.x; o.h[1] = (bf16_t)v.y;
    o.h[2] = (bf16_t)v.z; o.h[3] = (bf16_t)v.w;
    reinterpret_cast<uint2*>(out)[i] = o.u;
  }
}

__global__ __launch_bounds__(256) void cast4_kernel(const float* __restrict__ i0, const float* __restrict__ i1,
                                                    const float* __restrict__ i2, const float* __restrict__ i3,
                                                    bf16_t* o0, bf16_t* o1, bf16_t* o2, bf16_t* o3, int n4) {
  int z = blockIdx.y;
  const float* in = (z == 0) ? i0 : (z == 1) ? i1 : (z == 2) ? i2 : i3;
  bf16_t* out = (z == 0) ? o0 : (z == 1) ? o1 : (z == 2) ? o2 : o3;
  int i = blockIdx.x * 256 + threadIdx.x;
  if (i < n4) {
    float4 v = reinterpret_cast<const float4*>(in)[i];
    union { bf16_t h[4]; uint2 u; } o;
    o.h[0] = (bf16_t)v.x; o.h[1] = (bf16_t)v.y;
    o.h[2] = (bf16_t)v.z; o.h[3] = (bf16_t)v.w;
    reinterpret_cast<uint2*>(out)[i] = o.u;
  }
}

// ---------------------------------------------------------------------------
// Fused QKV GEMM with T3+T4 phase interleave.
// BM=BN=256, BK=32, 8 waves (2Mx4N, 128x64/wave). 3-buffer LDS ring (96KB).
// Per K-tile: 2 phases {ds_read || 2 gll stage(t+2) -> barrier -> lgkmcnt(0)
// -> setprio 16 MFMA -> barrier}; vmcnt(4) once per tile (retires t+1,
// leaves t+2's 4 loads in flight -- never drains to 0 until the tail).
// Swizzle (64B rows): read chunk ^= (row>>1)&3, gll src chunk (l&3)^((l>>3)&3)
// -> structural 2-way only (free).
// ---------------------------------------------------------------------------
__global__ __launch_bounds__(512, 2)
void qkv_gemm8(const bf16_t* __restrict__ xb,
               const bf16_t* __restrict__ Wqb, const bf16_t* __restrict__ Wkb,
               const bf16_t* __restrict__ Wvb,
               const float* __restrict__ bq, const float* __restrict__ bk,
               const float* __restrict__ bv,
               bf16_t* __restrict__ Qh, bf16_t* __restrict__ Kh,
               bf16_t* __restrict__ VTt) {
  __shared__ __align__(16) bf16_t lds[3][16384];  // per buf: A[256x32] @0, B[256x32] @8192

  const int raw = blockIdx.x;                     // 192 blocks
  const int swz = (raw & 7) * 24 + (raw >> 3);    // XCD-bijective (192 % 8 == 0)
  const int mt = swz / 12, nt = swz % 12;
  const int m0 = mt * 256;
  const int z = nt >> 2;                          // 0:Q 1:K 2:V (block-uniform)
  const int n0z = (nt & 3) * 256;
  const bf16_t* Bw  = (z == 0) ? Wqb : (z == 1) ? Wkb : Wvb;
  const float* bias = (z == 0) ? bq  : (z == 1) ? bk  : bv;

  const int tid = threadIdx.x, lane = tid & 63, w = tid >> 6;
  const int wm = w >> 2, wn = w & 3;              // 2 x 4 wave grid
  const int lrow = lane & 15, lkg = lane >> 4;
  const int rsw = (lrow >> 1) & 3;                // read-side XOR bits

  // staging lane geometry: linear LDS dest, inverse-swizzled global source
  const int sr = lane >> 2;                       // 0..15 rows in a gll unit
  const int sc = ((lane & 3) ^ ((lane >> 3) & 3)) * 8;
  const bf16_t* asrc = xb + (size_t)(m0 + w * 32 + sr) * 1024 + sc;
  const bf16_t* bsrc = Bw + (size_t)(n0z + w * 32 + sr) * 1024 + sc;

  f32x4 acc[8][4] = {};

  auto stageA = [&](int t) {
    const int k0 = t << 5;
    bf16_t* dst = &lds[t % 3][w * 1024];
    load_lds16(asrc + k0, dst);
    load_lds16(asrc + 16 * 1024 + k0, dst + 512);
  };
  auto stageB = [&](int t) {
    const int k0 = t << 5;
    bf16_t* dst = &lds[t % 3][8192 + w * 1024];
    load_lds16(bsrc + k0, dst);
    load_lds16(bsrc + 16 * 1024 + k0, dst + 512);
  };

  stageA(0); stageB(0); stageA(1); stageB(1);
  asm volatile("s_waitcnt vmcnt(4)" ::: "memory");  // tile 0 landed; tile 1 in flight
  __builtin_amdgcn_s_barrier();
  asm volatile("" ::: "memory");

  for (int t = 0; t < 32; ++t) {
    const bf16_t* Ab = &lds[t % 3][0];
    const bf16_t* Bb = &lds[t % 3][8192];

    // ---- phase 0: read B(4) + A-half0(4), stage A(t+2), MFMA m=0..3
    bf16x8 bfr[4], afr[4];
#pragma unroll
    for (int n = 0; n < 4; ++n) {
      const int row = wn * 64 + n * 16 + lrow;
      bfr[n] = *reinterpret_cast<const bf16x8*>(Bb + row * 32 + ((lkg ^ rsw) << 3));
    }
#pragma unroll
    for (int i = 0; i < 4; ++i) {
      const int row = wm * 128 + i * 16 + lrow;
      afr[i] = *reinterpret_cast<const bf16x8*>(Ab + row * 32 + ((lkg ^ rsw) << 3));
    }
    if (t + 2 < 32) stageA(t + 2);
    asm volatile("" ::: "memory");
    __builtin_amdgcn_s_barrier();
    asm volatile("s_waitcnt lgkmcnt(0)" ::: "memory");
    __builtin_amdgcn_s_setprio(1);
#pragma unroll
    for (int i = 0; i < 4; ++i)
#pragma unroll
      for (int n = 0; n < 4; ++n)
        acc[i][n] = __builtin_amdgcn_mfma_f32_16x16x32_bf16(afr[i], bfr[n], acc[i][n], 0, 0, 0);
    __builtin_amdgcn_s_setprio(0);
    asm volatile("" ::: "memory");
    __builtin_amdgcn_s_barrier();
    asm volatile("" ::: "memory");

    // ---- phase 1: read A-half1(4), stage B(t+2), MFMA m=4..7, counted vmcnt
#pragma unroll
    for (int i = 0; i < 4; ++i) {
      const int row = wm * 128 + (4 + i) * 16 + lrow;
      afr[i] = *reinterpret_cast<const bf16x8*>(Ab + row * 32 + ((lkg ^ rsw) << 3));
    }
    if (t + 2 < 32) stageB(t + 2);
    asm volatile("" ::: "memory");
    __builtin_amdgcn_s_barrier();
    asm volatile("s_waitcnt lgkmcnt(0)" ::: "memory");
    __builtin_amdgcn_s_setprio(1);
#pragma unroll
    for (int i = 0; i < 4; ++i)
#pragma unroll
      for (int n = 0; n < 4; ++n)
        acc[4 + i][n] = __builtin_amdgcn_mfma_f32_16x16x32_bf16(afr[i], bfr[n], acc[4 + i][n], 0, 0, 0);
    __builtin_amdgcn_s_setprio(0);
    if (t < 30) {
      asm volatile("s_waitcnt vmcnt(4)" ::: "memory");  // t+1 landed; t+2 still in flight
    } else {
      asm volatile("s_waitcnt vmcnt(0)" ::: "memory");  // tail drain
    }
    __builtin_amdgcn_s_barrier();
    asm volatile("" ::: "memory");
  }

#pragma unroll
  for (int m = 0; m < 8; ++m)
#pragma unroll
    for (int n = 0; n < 4; ++n)
#pragma unroll
      for (int r = 0; r < 4; ++r) {
        const int grow = m0 + wm * 128 + m * 16 + lkg * 4 + r;  // token row
        const int colz = n0z + wn * 64 + n * 16 + lrow;         // feature within z
        float val = acc[m][n][r] + bias[colz];
        const int bb = grow >> 11, tok = grow & 2047;
        const int hh = colz >> 6, dd = colz & 63;
        if (z == 2) {
          VTt[((((size_t)(bb * NH + hh) * 32 + (tok >> 6)) * 64 + dd) << 6) + (tok & 63)] = (bf16_t)val;
        } else {
          bf16_t* outp = (z == 0) ? Qh : Kh;
          outp[(((size_t)(bb * NH + hh) * NN + tok) << 6) + dd] = (bf16_t)val;
        }
      }
}

// C[m][n] = sum_k A[m][k] * Bw[n][k], K=1024. 128x128 tile, BK=32, 4 waves 2x2.
__device__ __forceinline__ void gemm_tile(const bf16_t* __restrict__ A,
                                          const bf16_t* __restrict__ Bw,
                                          bf16_t* As, bf16_t* Bs,
                                          int m0, int n0, f32x4 acc[4][4]) {
  const int tid  = threadIdx.x;
  const int lane = tid & 63;
  const int wid  = tid >> 6;
  const int wr = wid >> 1, wc = wid & 1;
  const int lrow = lane & 15, lkg = lane >> 4;
  const int srow = lane >> 2, scol = (lane & 3) * 8;

  for (int k0 = 0; k0 < 1024; k0 += 32) {
#pragma unroll
    for (int i = 0; i < 2; ++i) {
      const int rbase = (wid * 2 + i) * 16;
      load_lds16(A  + (size_t)(m0 + rbase + srow) * 1024 + k0 + scol, As + rbase * 32);
      load_lds16(Bw + (size_t)(n0 + rbase + srow) * 1024 + k0 + scol, Bs + rbase * 32);
    }
    __syncthreads();
    bf16x8 af[4], bf[4];
#pragma unroll
    for (int m = 0; m < 4; ++m)
      af[m] = *reinterpret_cast<const bf16x8*>(As + (wr * 64 + m * 16 + lrow) * 32 + lkg * 8);
#pragma unroll
    for (int n = 0; n < 4; ++n)
      bf[n] = *reinterpret_cast<const bf16x8*>(Bs + (wc * 64 + n * 16 + lrow) * 32 + lkg * 8);
#pragma unroll
    for (int m = 0; m < 4; ++m)
#pragma unroll
      for (int n = 0; n < 4; ++n)
        acc[m][n] = __builtin_amdgcn_mfma_f32_16x16x32_bf16(af[m], bf[n], acc[m][n], 0, 0, 0);
    __syncthreads();
  }
}

__global__ __launch_bounds__(256, 2)
void out_gemm(const bf16_t* __restrict__ AOb, const bf16_t* __restrict__ Wob,
              const float* __restrict__ bo, float* __restrict__ Cout) {
  __shared__ __align__(16) bf16_t As[128 * 32];
  __shared__ __align__(16) bf16_t Bs[128 * 32];
  const int m0 = blockIdx.y * 128, n0 = blockIdx.x * 128;
  f32x4 acc[4][4] = {};
  gemm_tile(AOb, Wob, As, Bs, m0, n0, acc);

  const int lane = threadIdx.x & 63;
  const int wid  = threadIdx.x >> 6;
  const int wr = wid >> 1, wc = wid & 1;
  const int lrow = lane & 15, lkg = lane >> 4;
#pragma unroll
  for (int m = 0; m < 4; ++m)
#pragma unroll
    for (int n = 0; n < 4; ++n)
#pragma unroll
      for (int r = 0; r < 4; ++r) {
        int row = m0 + wr * 64 + m * 16 + lkg * 4 + r;
        int col = n0 + wc * 64 + n * 16 + lrow;
        Cout[(size_t)row * 1024 + col] = acc[m][n][r] + bo[col];
      }
}

// ---------------------------------------------------------------------------
// Block-cooperative flash attention, swapped QK^T (unchanged, proven R3).
// ---------------------------------------------------------------------------
__global__ __launch_bounds__(256)
void attn_kernel(const bf16_t* __restrict__ Qh, const bf16_t* __restrict__ Kh,
                 const bf16_t* __restrict__ VTt, bf16_t* __restrict__ AO) {
  __shared__ __align__(16) bf16_t KV_lds[2][2][4096];
  __shared__ uint32_t P_lds[4][16][32];

  const int work = ((blockIdx.x & 7) << 7) | (blockIdx.x >> 3);
  const int qt = work & 31, h = (work >> 5) & 15, b = work >> 9;
  const int tid = threadIdx.x, lane = tid & 63, w = tid >> 6;
  const int lrow = lane & 15, lkg = lane >> 4;
  const int q0 = qt * 64;
  const int qb = q0 + w * 16;
  const int qrow = qb + lrow;
  const int rs7 = lrow & 7;

  const int srow8 = lane >> 3;
  const int sswz  = 8 * ((lane & 7) ^ srow8);

  const bf16_t* kbase = Kh  + ((size_t)(b * NH + h) * NN) * DHEAD;
  const bf16_t* vbase = VTt + ((size_t)(b * NH + h) * (NN / 64)) * DHEAD * 64;

  const bf16_t* qptr = Qh + (((size_t)(b * NH + h) * NN + qrow) << 6) + lkg * 8;
  bf16x8 qf0 = *reinterpret_cast<const bf16x8*>(qptr);
  bf16x8 qf1 = *reinterpret_cast<const bf16x8*>(qptr + 32);

  float m_run = -1e30f, l_run = 0.f;
  f32x4 o[4] = {};

  const int kstart = (q0 - WIN > 0) ? (q0 - WIN) : 0;
  const int kend = (q0 + 64 + WIN < NN) ? (q0 + 64 + WIN) : NN;
  const int nch = (kend - kstart) >> 6;
  const float scale = 0.125f;

  auto stage = [&](int bufi, int kc) {
#pragma unroll
    for (int j = 0; j < 2; ++j) {
      const int i = w * 2 + j;
      load_lds16(kbase + (((size_t)(kc + i * 8 + srow8)) << 6) + sswz,
                 &KV_lds[bufi][0][i * 512]);
      load_lds16(vbase + (((size_t)((kc >> 6) * 64 + i * 8 + srow8)) << 6) + sswz,
                 &KV_lds[bufi][1][i * 512]);
    }
  };

  stage(0, kstart);
  __syncthreads();

  for (int ic = 0; ic < nch; ++ic) {
    const int kc = kstart + ic * 64;
    const int bi = ic & 1;
    if (ic + 1 < nch) stage(bi ^ 1, kc + 64);

    const bf16_t* Kt = &KV_lds[bi][0][0];
    const bf16_t* Vt = &KV_lds[bi][1][0];

    f32x4 s[4];
#pragma unroll
    for (int t = 0; t < 4; ++t) {
      const bf16_t* kr = Kt + (t * 16 + lrow) * 64;
      bf16x8 kf0 = *reinterpret_cast<const bf16x8*>(kr + ((lkg ^ rs7) << 3));
      bf16x8 kf1 = *reinterpret_cast<const bf16x8*>(kr + (((4 + lkg) ^ rs7) << 3));
      f32x4 zz = {};
      zz = __builtin_amdgcn_mfma_f32_16x16x32_bf16(kf0, qf0, zz, 0, 0, 0);
      zz = __builtin_amdgcn_mfma_f32_16x16x32_bf16(kf1, qf1, zz, 0, 0, 0);
      s[t] = zz;
    }

    bf16x8 vf0[4], vf1[4];
#pragma unroll
    for (int f = 0; f < 4; ++f) {
      const bf16_t* vr = Vt + (f * 16 + lrow) * 64;
      vf0[f] = *reinterpret_cast<const bf16x8*>(vr + ((lkg ^ rs7) << 3));
      vf1[f] = *reinterpret_cast<const bf16x8*>(vr + (((4 + lkg) ^ rs7) << 3));
    }

    const bool needs_mask = (kc < qb - 113) || (kc > qb + 65);
    float p[4][4];
    float mloc = -1e30f, rsum = 0.f;
    if (needs_mask) {
      float v[4][4];
#pragma unroll
      for (int t = 0; t < 4; ++t)
#pragma unroll
        for (int r = 0; r < 4; ++r) {
          int k = kc + t * 16 + lkg * 4 + r;
          int d = qrow - k;
          bool ok = (unsigned)(d + WIN) <= 2u * WIN;
          v[t][r] = ok ? s[t][r] * scale : -1e30f;
          mloc = fmaxf(mloc, v[t][r]);
        }
      mloc = fmaxf(mloc, __shfl_xor(mloc, 16, 64));
      mloc = fmaxf(mloc, __shfl_xor(mloc, 32, 64));
      float mn = fmaxf(m_run, mloc);
      float corr = __expf(m_run - mn);
      m_run = mn;
#pragma unroll
      for (int t = 0; t < 4; ++t)
#pragma unroll
        for (int r = 0; r < 4; ++r) {
          int k = kc + t * 16 + lkg * 4 + r;
          int d = qrow - k;
          bool ok = (unsigned)(d + WIN) <= 2u * WIN;
          p[t][r] = ok ? __expf(v[t][r] - mn) : 0.f;
          rsum += p[t][r];
        }
      rsum += __shfl_xor(rsum, 16, 64);
      rsum += __shfl_xor(rsum, 32, 64);
      l_run = l_run * corr + rsum;
#pragma unroll
      for (int f = 0; f < 4; ++f) o[f] *= corr;
    } else {
      float v[4][4];
#pragma unroll
      for (int t = 0; t < 4; ++t)
#pragma unroll
        for (int r = 0; r < 4; ++r) {
          v[t][r] = s[t][r] * scale;
          mloc = fmaxf(mloc, v[t][r]);
        }
      mloc = fmaxf(mloc, __shfl_xor(mloc, 16, 64));
      mloc = fmaxf(mloc, __shfl_xor(mloc, 32, 64));
      float mn = fmaxf(m_run, mloc);
      float corr = __expf(m_run - mn);
      m_run = mn;
#pragma unroll
      for (int t = 0; t < 4; ++t)
#pragma unroll
        for (int r = 0; r < 4; ++r) {
          p[t][r] = __expf(v[t][r] - mn);
          rsum += p[t][r];
        }
      rsum += __shfl_xor(rsum, 16, 64);
      rsum += __shfl_xor(rsum, 32, 64);
      l_run = l_run * corr + rsum;
#pragma unroll
      for (int f = 0; f < 4; ++f) o[f] *= corr;
    }

    uint32_t* prow = &P_lds[w][lrow][0];
#pragma unroll
    for (int t = 0; t < 4; ++t)
#pragma unroll
      for (int c = 0; c < 2; ++c) {
        union { bf16_t hh[2]; uint32_t u; } pk;
        pk.hh[0] = (bf16_t)p[t][2 * c];
        pk.hh[1] = (bf16_t)p[t][2 * c + 1];
        int L = 8 * t + 2 * lkg + c;
        int pos = (((L >> 2) ^ rs7) << 2) | (L & 3);
        prow[pos] = pk.u;
      }
    asm volatile("" ::: "memory");
    const bf16_t* prd = reinterpret_cast<const bf16_t*>(&P_lds[w][lrow][0]);
    bf16x8 pa0 = *reinterpret_cast<const bf16x8*>(prd + ((lkg ^ rs7) << 3));
    bf16x8 pa1 = *reinterpret_cast<const bf16x8*>(prd + (((4 + lkg) ^ rs7) << 3));

#pragma unroll
    for (int f = 0; f < 4; ++f) {
      o[f] = __builtin_amdgcn_mfma_f32_16x16x32_bf16(vf0[f], pa0, o[f], 0, 0, 0);
      o[f] = __builtin_amdgcn_mfma_f32_16x16x32_bf16(vf1[f], pa1, o[f], 0, 0, 0);
    }
    __syncthreads();
  }

  float inv = 1.0f / l_run;
#pragma unroll
  for (int f = 0; f < 4; ++f) {
    union { bf16_t hh[4]; uint2 u; } ov;
#pragma unroll
    for (int r = 0; r < 4; ++r) ov.hh[r] = (bf16_t)(o[f][r] * inv);
    bf16_t* op = AO + (size_t)(b * NN + qrow) * ND + h * DHEAD + f * 16 + lkg * 4;
    *reinterpret_cast<uint2*>(op) = ov.u;
  }
}

extern "C" void kernel_launch(void* const* d_in, const int* in_sizes, int n_in,
                              void* d_out, int out_size, void* d_ws, size_t ws_size,
                              hipStream_t stream) {
  const float* x  = (const float*)d_in[0];
  const float* Wq = (const float*)d_in[1];
  const float* bq = (const float*)d_in[2];
  const float* Wk = (const float*)d_in[3];
  const float* bk = (const float*)d_in[4];
  const float* Wv = (const float*)d_in[5];
  const float* bv = (const float*)d_in[6];
  const float* Wo = (const float*)d_in[7];
  const float* bo = (const float*)d_in[8];
  float* out = (float*)d_out;

  bf16_t* ws  = (bf16_t*)d_ws;
  bf16_t* xb  = ws;
  bf16_t* Wqb = xb  + 4194304;
  bf16_t* Wkb = Wqb + 1048576;
  bf16_t* Wvb = Wkb + 1048576;
  bf16_t* Wob = Wvb + 1048576;
  bf16_t* Qh  = Wob + 1048576;
  bf16_t* Kh  = Qh  + 4194304;
  bf16_t* VTt = Kh  + 4194304;
  bf16_t* AOb = VTt + 4194304;

  cast_kernel<<<4096, 256, 0, stream>>>(x, xb, 1048576);
  cast4_kernel<<<dim3(1024, 4), 256, 0, stream>>>(Wq, Wk, Wv, Wo, Wqb, Wkb, Wvb, Wob, 262144);

  qkv_gemm8<<<192, 512, 0, stream>>>(xb, Wqb, Wkb, Wvb, bq, bk, bv, Qh, Kh, VTt);
  attn_kernel<<<1024, 256, 0, stream>>>(Qh, Kh, VTt, AOb);
  out_gemm<<<dim3(8, 32), 256, 0, stream>>>(AOb, Wob, bo, out);
}

// Round 7
// 97.120 us; speedup vs baseline: 1.2199x; 1.2199x over previous
//
#include <hip/hip_runtime.h>
#include <hip/hip_bf16.h>
#include <stdint.h>

typedef __bf16 bf16_t;
typedef __bf16 bf16x8 __attribute__((ext_vector_type(8)));
typedef float f32x4 __attribute__((ext_vector_type(4)));

#define NB 2
#define NN 2048
#define ND 1024
#define NH 16
#define DHEAD 64
#define WIN 128

__device__ __forceinline__ void load_lds16(const void* g, void* l) {
  __builtin_amdgcn_global_load_lds(
      (const __attribute__((address_space(1))) uint32_t*)g,
      (__attribute__((address_space(3))) uint32_t*)l, 16, 0, 0);
}

// single merged cast launch: x (1048576 float4) + 4 weights (262144 float4 each)
__global__ __launch_bounds__(256)
void cast_all(const float* __restrict__ x,
              const float* __restrict__ Wq, const float* __restrict__ Wk,
              const float* __restrict__ Wv, const float* __restrict__ Wo,
              bf16_t* __restrict__ xb,
              bf16_t* __restrict__ Wqb, bf16_t* __restrict__ Wkb,
              bf16_t* __restrict__ Wvb, bf16_t* __restrict__ Wob) {
  int i = blockIdx.x * 256 + threadIdx.x;   // 0 .. 2097151
  const float* in;
  bf16_t* out;
  int off;
  if (i < 1048576) {
    in = x; out = xb; off = i;
  } else {
    int j = i - 1048576;
    int wsel = j >> 18;
    off = j & 262143;
    in  = (wsel == 0) ? Wq  : (wsel == 1) ? Wk  : (wsel == 2) ? Wv  : Wo;
    out = (wsel == 0) ? Wqb : (wsel == 1) ? Wkb : (wsel == 2) ? Wvb : Wob;
  }
  float4 v = reinterpret_cast<const float4*>(in)[off];
  union { bf16_t h[4]; uint2 u; } o;
  o.h[0] = (bf16_t)v.x; o.h[1] = (bf16_t)v.y;
  o.h[2] = (bf16_t)v.z; o.h[3] = (bf16_t)v.w;
  reinterpret_cast<uint2*>(out)[off] = o.u;
}

// ---------------------------------------------------------------------------
// Double-buffered m97-style tile: C[m][n] = sum_k A[m][k]*Bw[n][k], K=1024.
// 128x128 tile, BK=32, 4 waves 2x2. stage(t+1) issued BEFORE computing t;
// the single __syncthreads per iter drains it while compute overlaps.
// LDS 32KB -> 3+ blocks/CU (inter-block TLP covers residual latency).
// ---------------------------------------------------------------------------
__device__ __forceinline__ void gemm_tile_db(const bf16_t* __restrict__ A,
                                             const bf16_t* __restrict__ Bw,
                                             bf16_t* As, bf16_t* Bs,  // each [2*4096]
                                             int m0, int n0, f32x4 acc[4][4]) {
  const int tid  = threadIdx.x;
  const int lane = tid & 63;
  const int wid  = tid >> 6;
  const int wr = wid >> 1, wc = wid & 1;
  const int lrow = lane & 15, lkg = lane >> 4;
  const int srow = lane >> 2, scol = (lane & 3) * 8;

  const bf16_t* abase = A  + (size_t)(m0 + srow) * 1024 + scol;
  const bf16_t* bbase = Bw + (size_t)(n0 + srow) * 1024 + scol;

  auto stage = [&](int buf, int k0) {
#pragma unroll
    for (int i = 0; i < 2; ++i) {
      const int rbase = (wid * 2 + i) * 16;
      load_lds16(abase + (size_t)rbase * 1024 + k0, As + buf * 4096 + rbase * 32);
      load_lds16(bbase + (size_t)rbase * 1024 + k0, Bs + buf * 4096 + rbase * 32);
    }
  };

  stage(0, 0);
  __syncthreads();                       // buf0 landed (implicit vmcnt(0) + barrier)

  for (int t = 0; t < 32; ++t) {
    if (t < 31) stage((t + 1) & 1, (t + 1) << 5);   // issue early; lands by next barrier
    const bf16_t* Ab = As + (t & 1) * 4096;
    const bf16_t* Bb = Bs + (t & 1) * 4096;
    bf16x8 af[4], bf[4];
#pragma unroll
    for (int m = 0; m < 4; ++m)
      af[m] = *reinterpret_cast<const bf16x8*>(Ab + (wr * 64 + m * 16 + lrow) * 32 + lkg * 8);
#pragma unroll
    for (int n = 0; n < 4; ++n)
      bf[n] = *reinterpret_cast<const bf16x8*>(Bb + (wc * 64 + n * 16 + lrow) * 32 + lkg * 8);
#pragma unroll
    for (int m = 0; m < 4; ++m)
#pragma unroll
      for (int n = 0; n < 4; ++n)
        acc[m][n] = __builtin_amdgcn_mfma_f32_16x16x32_bf16(af[m], bf[n], acc[m][n], 0, 0, 0);
    __syncthreads();                     // drains stage(t+1) + protects buffer reuse
  }
}

// z=0: Qh[b][h][tok][64], z=1: Kh same, z=2: VTt[b][h][tile][d][64]
__global__ __launch_bounds__(256, 2)
void qkv_gemm(const bf16_t* __restrict__ xb,
              const bf16_t* __restrict__ Wqb, const bf16_t* __restrict__ Wkb,
              const bf16_t* __restrict__ Wvb,
              const float* __restrict__ bq, const float* __restrict__ bk,
              const float* __restrict__ bv,
              bf16_t* __restrict__ Qh, bf16_t* __restrict__ Kh,
              bf16_t* __restrict__ VTt) {
  __shared__ __align__(16) bf16_t As[2 * 4096];
  __shared__ __align__(16) bf16_t Bs[2 * 4096];
  const int z = blockIdx.z;
  const bf16_t* Bw  = (z == 0) ? Wqb : (z == 1) ? Wkb : Wvb;
  const float* bias = (z == 0) ? bq  : (z == 1) ? bk  : bv;
  const int m0 = blockIdx.y * 128, n0 = blockIdx.x * 128;
  f32x4 acc[4][4] = {};
  gemm_tile_db(xb, Bw, As, Bs, m0, n0, acc);

  const int lane = threadIdx.x & 63;
  const int wid  = threadIdx.x >> 6;
  const int wr = wid >> 1, wc = wid & 1;
  const int lrow = lane & 15, lkg = lane >> 4;
#pragma unroll
  for (int m = 0; m < 4; ++m)
#pragma unroll
    for (int n = 0; n < 4; ++n)
#pragma unroll
      for (int r = 0; r < 4; ++r) {
        int row = m0 + wr * 64 + m * 16 + lkg * 4 + r;   // token index (global)
        int col = n0 + wc * 64 + n * 16 + lrow;          // feature index
        float val = acc[m][n][r] + bias[col];
        int bb = row >> 11, tok = row & 2047;
        int hh = col >> 6,  dd = col & 63;
        if (z == 2) {
          VTt[((((size_t)(bb * NH + hh) * 32 + (tok >> 6)) * 64 + dd) << 6) + (tok & 63)] = (bf16_t)val;
        } else {
          bf16_t* outp = (z == 0) ? Qh : Kh;
          outp[(((size_t)(bb * NH + hh) * NN + tok) << 6) + dd] = (bf16_t)val;
        }
      }
}

__global__ __launch_bounds__(256, 2)
void out_gemm(const bf16_t* __restrict__ AOb, const bf16_t* __restrict__ Wob,
              const float* __restrict__ bo, float* __restrict__ Cout) {
  __shared__ __align__(16) bf16_t As[2 * 4096];
  __shared__ __align__(16) bf16_t Bs[2 * 4096];
  const int m0 = blockIdx.y * 128, n0 = blockIdx.x * 128;
  f32x4 acc[4][4] = {};
  gemm_tile_db(AOb, Wob, As, Bs, m0, n0, acc);

  const int lane = threadIdx.x & 63;
  const int wid  = threadIdx.x >> 6;
  const int wr = wid >> 1, wc = wid & 1;
  const int lrow = lane & 15, lkg = lane >> 4;
#pragma unroll
  for (int m = 0; m < 4; ++m)
#pragma unroll
    for (int n = 0; n < 4; ++n)
#pragma unroll
      for (int r = 0; r < 4; ++r) {
        int row = m0 + wr * 64 + m * 16 + lkg * 4 + r;
        int col = n0 + wc * 64 + n * 16 + lrow;
        Cout[(size_t)row * 1024 + col] = acc[m][n][r] + bo[col];
      }
}

// ---------------------------------------------------------------------------
// Block-cooperative flash attention, swapped QK^T (unchanged, proven R3).
// ---------------------------------------------------------------------------
__global__ __launch_bounds__(256)
void attn_kernel(const bf16_t* __restrict__ Qh, const bf16_t* __restrict__ Kh,
                 const bf16_t* __restrict__ VTt, bf16_t* __restrict__ AO) {
  __shared__ __align__(16) bf16_t KV_lds[2][2][4096];
  __shared__ uint32_t P_lds[4][16][32];

  const int work = ((blockIdx.x & 7) << 7) | (blockIdx.x >> 3);
  const int qt = work & 31, h = (work >> 5) & 15, b = work >> 9;
  const int tid = threadIdx.x, lane = tid & 63, w = tid >> 6;
  const int lrow = lane & 15, lkg = lane >> 4;
  const int q0 = qt * 64;
  const int qb = q0 + w * 16;
  const int qrow = qb + lrow;
  const int rs7 = lrow & 7;

  const int srow8 = lane >> 3;
  const int sswz  = 8 * ((lane & 7) ^ srow8);

  const bf16_t* kbase = Kh  + ((size_t)(b * NH + h) * NN) * DHEAD;
  const bf16_t* vbase = VTt + ((size_t)(b * NH + h) * (NN / 64)) * DHEAD * 64;

  const bf16_t* qptr = Qh + (((size_t)(b * NH + h) * NN + qrow) << 6) + lkg * 8;
  bf16x8 qf0 = *reinterpret_cast<const bf16x8*>(qptr);
  bf16x8 qf1 = *reinterpret_cast<const bf16x8*>(qptr + 32);

  float m_run = -1e30f, l_run = 0.f;
  f32x4 o[4] = {};

  const int kstart = (q0 - WIN > 0) ? (q0 - WIN) : 0;
  const int kend = (q0 + 64 + WIN < NN) ? (q0 + 64 + WIN) : NN;
  const int nch = (kend - kstart) >> 6;
  const float scale = 0.125f;

  auto stage = [&](int bufi, int kc) {
#pragma unroll
    for (int j = 0; j < 2; ++j) {
      const int i = w * 2 + j;
      load_lds16(kbase + (((size_t)(kc + i * 8 + srow8)) << 6) + sswz,
                 &KV_lds[bufi][0][i * 512]);
      load_lds16(vbase + (((size_t)((kc >> 6) * 64 + i * 8 + srow8)) << 6) + sswz,
                 &KV_lds[bufi][1][i * 512]);
    }
  };

  stage(0, kstart);
  __syncthreads();

  for (int ic = 0; ic < nch; ++ic) {
    const int kc = kstart + ic * 64;
    const int bi = ic & 1;
    if (ic + 1 < nch) stage(bi ^ 1, kc + 64);

    const bf16_t* Kt = &KV_lds[bi][0][0];
    const bf16_t* Vt = &KV_lds[bi][1][0];

    f32x4 s[4];
#pragma unroll
    for (int t = 0; t < 4; ++t) {
      const bf16_t* kr = Kt + (t * 16 + lrow) * 64;
      bf16x8 kf0 = *reinterpret_cast<const bf16x8*>(kr + ((lkg ^ rs7) << 3));
      bf16x8 kf1 = *reinterpret_cast<const bf16x8*>(kr + (((4 + lkg) ^ rs7) << 3));
      f32x4 zz = {};
      zz = __builtin_amdgcn_mfma_f32_16x16x32_bf16(kf0, qf0, zz, 0, 0, 0);
      zz = __builtin_amdgcn_mfma_f32_16x16x32_bf16(kf1, qf1, zz, 0, 0, 0);
      s[t] = zz;
    }

    bf16x8 vf0[4], vf1[4];
#pragma unroll
    for (int f = 0; f < 4; ++f) {
      const bf16_t* vr = Vt + (f * 16 + lrow) * 64;
      vf0[f] = *reinterpret_cast<const bf16x8*>(vr + ((lkg ^ rs7) << 3));
      vf1[f] = *reinterpret_cast<const bf16x8*>(vr + (((4 + lkg) ^ rs7) << 3));
    }

    const bool needs_mask = (kc < qb - 113) || (kc > qb + 65);
    float p[4][4];
    float mloc = -1e30f, rsum = 0.f;
    if (needs_mask) {
      float v[4][4];
#pragma unroll
      for (int t = 0; t < 4; ++t)
#pragma unroll
        for (int r = 0; r < 4; ++r) {
          int k = kc + t * 16 + lkg * 4 + r;
          int d = qrow - k;
          bool ok = (unsigned)(d + WIN) <= 2u * WIN;
          v[t][r] = ok ? s[t][r] * scale : -1e30f;
          mloc = fmaxf(mloc, v[t][r]);
        }
      mloc = fmaxf(mloc, __shfl_xor(mloc, 16, 64));
      mloc = fmaxf(mloc, __shfl_xor(mloc, 32, 64));
      float mn = fmaxf(m_run, mloc);
      float corr = __expf(m_run - mn);
      m_run = mn;
#pragma unroll
      for (int t = 0; t < 4; ++t)
#pragma unroll
        for (int r = 0; r < 4; ++r) {
          int k = kc + t * 16 + lkg * 4 + r;
          int d = qrow - k;
          bool ok = (unsigned)(d + WIN) <= 2u * WIN;
          p[t][r] = ok ? __expf(v[t][r] - mn) : 0.f;
          rsum += p[t][r];
        }
      rsum += __shfl_xor(rsum, 16, 64);
      rsum += __shfl_xor(rsum, 32, 64);
      l_run = l_run * corr + rsum;
#pragma unroll
      for (int f = 0; f < 4; ++f) o[f] *= corr;
    } else {
      float v[4][4];
#pragma unroll
      for (int t = 0; t < 4; ++t)
#pragma unroll
        for (int r = 0; r < 4; ++r) {
          v[t][r] = s[t][r] * scale;
          mloc = fmaxf(mloc, v[t][r]);
        }
      mloc = fmaxf(mloc, __shfl_xor(mloc, 16, 64));
      mloc = fmaxf(mloc, __shfl_xor(mloc, 32, 64));
      float mn = fmaxf(m_run, mloc);
      float corr = __expf(m_run - mn);
      m_run = mn;
#pragma unroll
      for (int t = 0; t < 4; ++t)
#pragma unroll
        for (int r = 0; r < 4; ++r) {
          p[t][r] = __expf(v[t][r] - mn);
          rsum += p[t][r];
        }
      rsum += __shfl_xor(rsum, 16, 64);
      rsum += __shfl_xor(rsum, 32, 64);
      l_run = l_run * corr + rsum;
#pragma unroll
      for (int f = 0; f < 4; ++f) o[f] *= corr;
    }

    uint32_t* prow = &P_lds[w][lrow][0];
#pragma unroll
    for (int t = 0; t < 4; ++t)
#pragma unroll
      for (int c = 0; c < 2; ++c) {
        union { bf16_t hh[2]; uint32_t u; } pk;
        pk.hh[0] = (bf16_t)p[t][2 * c];
        pk.hh[1] = (bf16_t)p[t][2 * c + 1];
        int L = 8 * t + 2 * lkg + c;
        int pos = (((L >> 2) ^ rs7) << 2) | (L & 3);
        prow[pos] = pk.u;
      }
    asm volatile("" ::: "memory");
    const bf16_t* prd = reinterpret_cast<const bf16_t*>(&P_lds[w][lrow][0]);
    bf16x8 pa0 = *reinterpret_cast<const bf16x8*>(prd + ((lkg ^ rs7) << 3));
    bf16x8 pa1 = *reinterpret_cast<const bf16x8*>(prd + (((4 + lkg) ^ rs7) << 3));

#pragma unroll
    for (int f = 0; f < 4; ++f) {
      o[f] = __builtin_amdgcn_mfma_f32_16x16x32_bf16(vf0[f], pa0, o[f], 0, 0, 0);
      o[f] = __builtin_amdgcn_mfma_f32_16x16x32_bf16(vf1[f], pa1, o[f], 0, 0, 0);
    }
    __syncthreads();
  }

  float inv = 1.0f / l_run;
#pragma unroll
  for (int f = 0; f < 4; ++f) {
    union { bf16_t hh[4]; uint2 u; } ov;
#pragma unroll
    for (int r = 0; r < 4; ++r) ov.hh[r] = (bf16_t)(o[f][r] * inv);
    bf16_t* op = AO + (size_t)(b * NN + qrow) * ND + h * DHEAD + f * 16 + lkg * 4;
    *reinterpret_cast<uint2*>(op) = ov.u;
  }
}

extern "C" void kernel_launch(void* const* d_in, const int* in_sizes, int n_in,
                              void* d_out, int out_size, void* d_ws, size_t ws_size,
                              hipStream_t stream) {
  const float* x  = (const float*)d_in[0];
  const float* Wq = (const float*)d_in[1];
  const float* bq = (const float*)d_in[2];
  const float* Wk = (const float*)d_in[3];
  const float* bk = (const float*)d_in[4];
  const float* Wv = (const float*)d_in[5];
  const float* bv = (const float*)d_in[6];
  const float* Wo = (const float*)d_in[7];
  const float* bo = (const float*)d_in[8];
  float* out = (float*)d_out;

  bf16_t* ws  = (bf16_t*)d_ws;
  bf16_t* xb  = ws;
  bf16_t* Wqb = xb  + 4194304;
  bf16_t* Wkb = Wqb + 1048576;
  bf16_t* Wvb = Wkb + 1048576;
  bf16_t* Wob = Wvb + 1048576;
  bf16_t* Qh  = Wob + 1048576;
  bf16_t* Kh  = Qh  + 4194304;
  bf16_t* VTt = Kh  + 4194304;
  bf16_t* AOb = VTt + 4194304;

  cast_all<<<8192, 256, 0, stream>>>(x, Wq, Wk, Wv, Wo, xb, Wqb, Wkb, Wvb, Wob);

  qkv_gemm<<<dim3(8, 32, 3), 256, 0, stream>>>(xb, Wqb, Wkb, Wvb, bq, bk, bv, Qh, Kh, VTt);
  attn_kernel<<<1024, 256, 0, stream>>>(Qh, Kh, VTt, AOb);
  out_gemm<<<dim3(8, 32), 256, 0, stream>>>(AOb, Wob, bo, out);
}

// Round 8
// 91.039 us; speedup vs baseline: 1.3014x; 1.0668x over previous
//
#include <hip/hip_runtime.h>
#include <hip/hip_bf16.h>
#include <stdint.h>

typedef __bf16 bf16_t;
typedef __bf16 bf16x8 __attribute__((ext_vector_type(8)));
typedef float f32x4 __attribute__((ext_vector_type(4)));

#define NB 2
#define NN 2048
#define ND 1024
#define NH 16
#define DHEAD 64
#define WIN 128

__device__ __forceinline__ void load_lds16(const void* g, void* l) {
  __builtin_amdgcn_global_load_lds(
      (const __attribute__((address_space(1))) uint32_t*)g,
      (__attribute__((address_space(3))) uint32_t*)l, 16, 0, 0);
}

// single merged cast launch: x (1048576 float4) + 4 weights (262144 float4 each)
__global__ __launch_bounds__(256)
void cast_all(const float* __restrict__ x,
              const float* __restrict__ Wq, const float* __restrict__ Wk,
              const float* __restrict__ Wv, const float* __restrict__ Wo,
              bf16_t* __restrict__ xb,
              bf16_t* __restrict__ Wqb, bf16_t* __restrict__ Wkb,
              bf16_t* __restrict__ Wvb, bf16_t* __restrict__ Wob) {
  int i = blockIdx.x * 256 + threadIdx.x;   // 0 .. 2097151
  const float* in;
  bf16_t* out;
  int off;
  if (i < 1048576) {
    in = x; out = xb; off = i;
  } else {
    int j = i - 1048576;
    int wsel = j >> 18;
    off = j & 262143;
    in  = (wsel == 0) ? Wq  : (wsel == 1) ? Wk  : (wsel == 2) ? Wv  : Wo;
    out = (wsel == 0) ? Wqb : (wsel == 1) ? Wkb : (wsel == 2) ? Wvb : Wob;
  }
  float4 v = reinterpret_cast<const float4*>(in)[off];
  union { bf16_t h[4]; uint2 u; } o;
  o.h[0] = (bf16_t)v.x; o.h[1] = (bf16_t)v.y;
  o.h[2] = (bf16_t)v.z; o.h[3] = (bf16_t)v.w;
  reinterpret_cast<uint2*>(out)[off] = o.u;
}

// ---------------------------------------------------------------------------
// Double-buffered 128x128 tile, BK=32, 4 waves 2x2, conflict-free LDS swizzle
// (R6-verified): read chunk ^= (row>>1)&3; gll source chunk (l&3)^((l>>3)&3).
// stage(t+1) issued before compute(t); __syncthreads drains it under compute.
// ---------------------------------------------------------------------------
__device__ __forceinline__ void gemm_tile_db(const bf16_t* __restrict__ A,
                                             const bf16_t* __restrict__ Bw,
                                             bf16_t* As, bf16_t* Bs,  // each [2*4096]
                                             int m0, int n0, f32x4 acc[4][4]) {
  const int tid  = threadIdx.x;
  const int lane = tid & 63;
  const int wid  = tid >> 6;
  const int wr = wid >> 1, wc = wid & 1;
  const int lrow = lane & 15, lkg = lane >> 4;
  const int rsw = (lrow >> 1) & 3;                     // read-side XOR
  const int srow = lane >> 2;
  const int scol = ((lane & 3) ^ ((lane >> 3) & 3)) * 8;  // inverse-swizzled src

  const bf16_t* abase = A  + (size_t)(m0 + srow) * 1024 + scol;
  const bf16_t* bbase = Bw + (size_t)(n0 + srow) * 1024 + scol;

  auto stage = [&](int buf, int k0) {
#pragma unroll
    for (int i = 0; i < 2; ++i) {
      const int rbase = (wid * 2 + i) * 16;
      load_lds16(abase + (size_t)rbase * 1024 + k0, As + buf * 4096 + rbase * 32);
      load_lds16(bbase + (size_t)rbase * 1024 + k0, Bs + buf * 4096 + rbase * 32);
    }
  };

  stage(0, 0);
  __syncthreads();

  for (int t = 0; t < 32; ++t) {
    if (t < 31) stage((t + 1) & 1, (t + 1) << 5);
    const bf16_t* Ab = As + (t & 1) * 4096;
    const bf16_t* Bb = Bs + (t & 1) * 4096;
    bf16x8 af[4], bf[4];
#pragma unroll
    for (int m = 0; m < 4; ++m)
      af[m] = *reinterpret_cast<const bf16x8*>(Ab + (wr * 64 + m * 16 + lrow) * 32 + ((lkg ^ rsw) << 3));
#pragma unroll
    for (int n = 0; n < 4; ++n)
      bf[n] = *reinterpret_cast<const bf16x8*>(Bb + (wc * 64 + n * 16 + lrow) * 32 + ((lkg ^ rsw) << 3));
#pragma unroll
    for (int m = 0; m < 4; ++m)
#pragma unroll
      for (int n = 0; n < 4; ++n)
        acc[m][n] = __builtin_amdgcn_mfma_f32_16x16x32_bf16(af[m], bf[n], acc[m][n], 0, 0, 0);
    __syncthreads();
  }
}

// z=0: Qh[b][h][tok][64], z=1: Kh same, z=2: VTt[b][h][tile][d][64]
__global__ __launch_bounds__(256, 2)
void qkv_gemm(const bf16_t* __restrict__ xb,
              const bf16_t* __restrict__ Wqb, const bf16_t* __restrict__ Wkb,
              const bf16_t* __restrict__ Wvb,
              const float* __restrict__ bq, const float* __restrict__ bk,
              const float* __restrict__ bv,
              bf16_t* __restrict__ Qh, bf16_t* __restrict__ Kh,
              bf16_t* __restrict__ VTt) {
  __shared__ __align__(16) bf16_t As[2 * 4096];
  __shared__ __align__(16) bf16_t Bs[2 * 4096];
  const int z = blockIdx.z;
  const bf16_t* Bw  = (z == 0) ? Wqb : (z == 1) ? Wkb : Wvb;
  const float* bias = (z == 0) ? bq  : (z == 1) ? bk  : bv;
  const int m0 = blockIdx.y * 128, n0 = blockIdx.x * 128;
  f32x4 acc[4][4] = {};
  gemm_tile_db(xb, Bw, As, Bs, m0, n0, acc);

  const int lane = threadIdx.x & 63;
  const int wid  = threadIdx.x >> 6;
  const int wr = wid >> 1, wc = wid & 1;
  const int lrow = lane & 15, lkg = lane >> 4;
#pragma unroll
  for (int m = 0; m < 4; ++m)
#pragma unroll
    for (int n = 0; n < 4; ++n)
#pragma unroll
      for (int r = 0; r < 4; ++r) {
        int row = m0 + wr * 64 + m * 16 + lkg * 4 + r;   // token index (global)
        int col = n0 + wc * 64 + n * 16 + lrow;          // feature index
        float val = acc[m][n][r] + bias[col];
        int bb = row >> 11, tok = row & 2047;
        int hh = col >> 6,  dd = col & 63;
        if (z == 2) {
          VTt[((((size_t)(bb * NH + hh) * 32 + (tok >> 6)) * 64 + dd) << 6) + (tok & 63)] = (bf16_t)val;
        } else {
          bf16_t* outp = (z == 0) ? Qh : Kh;
          outp[(((size_t)(bb * NH + hh) * NN + tok) << 6) + dd] = (bf16_t)val;
        }
      }
}

// ---------------------------------------------------------------------------
// Output projection with in-block split-K: 512 threads, 8 waves.
// Waves 0-3 (group 0) compute K[0:512), waves 4-7 (group 1) K[512:1024),
// each group 2x2 waves over the 128x128 tile (wave-tile 64x64), own
// double-buffered LDS stream (4 x 16KB = 64KB). f32 LDS reduce at the end.
// Doubles resident waves on the grid-starved 256-block launch.
// ---------------------------------------------------------------------------
__global__ __launch_bounds__(512, 2)
void out_gemm2(const bf16_t* __restrict__ AOb, const bf16_t* __restrict__ Wob,
               const float* __restrict__ bo, float* __restrict__ Cout) {
  __shared__ __align__(16) bf16_t lds[32768];   // [g*2+buf][A 4096 | B 4096]

  const int m0 = blockIdx.y * 128, n0 = blockIdx.x * 128;
  const int tid = threadIdx.x, lane = tid & 63, w = tid >> 6;
  const int g = w >> 2;                          // K-group
  const int pair = w & 3;                        // wave-tile id within group
  const int wr = pair >> 1, wc = pair & 1;
  const int lrow = lane & 15, lkg = lane >> 4;
  const int rsw = (lrow >> 1) & 3;
  const int srow = lane >> 2;
  const int scol = ((lane & 3) ^ ((lane >> 3) & 3)) * 8;

  const bf16_t* abase = AOb + (size_t)(m0 + srow) * 1024 + g * 512 + scol;
  const bf16_t* bbase = Wob + (size_t)(n0 + srow) * 1024 + g * 512 + scol;

  f32x4 acc[4][4] = {};

  auto stage = [&](int buf, int k0) {
#pragma unroll
    for (int i = 0; i < 2; ++i) {
      const int rbase = (pair * 2 + i) * 16;
      bf16_t* seg = &lds[(g * 2 + buf) * 8192];
      load_lds16(abase + (size_t)rbase * 1024 + k0, seg + rbase * 32);
      load_lds16(bbase + (size_t)rbase * 1024 + k0, seg + 4096 + rbase * 32);
    }
  };

  stage(0, 0);
  __syncthreads();

  for (int t = 0; t < 16; ++t) {
    if (t < 15) stage((t + 1) & 1, (t + 1) << 5);
    const bf16_t* Ab = &lds[(g * 2 + (t & 1)) * 8192];
    const bf16_t* Bb = Ab + 4096;
    bf16x8 af[4], bf[4];
#pragma unroll
    for (int m = 0; m < 4; ++m)
      af[m] = *reinterpret_cast<const bf16x8*>(Ab + (wr * 64 + m * 16 + lrow) * 32 + ((lkg ^ rsw) << 3));
#pragma unroll
    for (int n = 0; n < 4; ++n)
      bf[n] = *reinterpret_cast<const bf16x8*>(Bb + (wc * 64 + n * 16 + lrow) * 32 + ((lkg ^ rsw) << 3));
#pragma unroll
    for (int m = 0; m < 4; ++m)
#pragma unroll
      for (int n = 0; n < 4; ++n)
        acc[m][n] = __builtin_amdgcn_mfma_f32_16x16x32_bf16(af[m], bf[n], acc[m][n], 0, 0, 0);
    __syncthreads();
  }

  // split-K reduce: group 1 parks partials in LDS (64KB), group 0 adds + stores
  float* fl = reinterpret_cast<float*>(lds);     // 16384 floats
  if (g == 1) {
#pragma unroll
    for (int m = 0; m < 4; ++m)
#pragma unroll
      for (int n = 0; n < 4; ++n)
#pragma unroll
        for (int r = 0; r < 4; ++r)
          fl[pair * 4096 + ((m * 4 + n) * 4 + r) * 64 + lane] = acc[m][n][r];
  }
  __syncthreads();
  if (g == 0) {
#pragma unroll
    for (int m = 0; m < 4; ++m)
#pragma unroll
      for (int n = 0; n < 4; ++n)
#pragma unroll
        for (int r = 0; r < 4; ++r) {
          int row = m0 + wr * 64 + m * 16 + lkg * 4 + r;
          int col = n0 + wc * 64 + n * 16 + lrow;
          float val = acc[m][n][r] + fl[pair * 4096 + ((m * 4 + n) * 4 + r) * 64 + lane] + bo[col];
          Cout[(size_t)row * 1024 + col] = val;
        }
  }
}

// ---------------------------------------------------------------------------
// Block-cooperative flash attention, swapped QK^T (unchanged, proven R3).
// ---------------------------------------------------------------------------
__global__ __launch_bounds__(256)
void attn_kernel(const bf16_t* __restrict__ Qh, const bf16_t* __restrict__ Kh,
                 const bf16_t* __restrict__ VTt, bf16_t* __restrict__ AO) {
  __shared__ __align__(16) bf16_t KV_lds[2][2][4096];
  __shared__ uint32_t P_lds[4][16][32];

  const int work = ((blockIdx.x & 7) << 7) | (blockIdx.x >> 3);
  const int qt = work & 31, h = (work >> 5) & 15, b = work >> 9;
  const int tid = threadIdx.x, lane = tid & 63, w = tid >> 6;
  const int lrow = lane & 15, lkg = lane >> 4;
  const int q0 = qt * 64;
  const int qb = q0 + w * 16;
  const int qrow = qb + lrow;
  const int rs7 = lrow & 7;

  const int srow8 = lane >> 3;
  const int sswz  = 8 * ((lane & 7) ^ srow8);

  const bf16_t* kbase = Kh  + ((size_t)(b * NH + h) * NN) * DHEAD;
  const bf16_t* vbase = VTt + ((size_t)(b * NH + h) * (NN / 64)) * DHEAD * 64;

  const bf16_t* qptr = Qh + (((size_t)(b * NH + h) * NN + qrow) << 6) + lkg * 8;
  bf16x8 qf0 = *reinterpret_cast<const bf16x8*>(qptr);
  bf16x8 qf1 = *reinterpret_cast<const bf16x8*>(qptr + 32);

  float m_run = -1e30f, l_run = 0.f;
  f32x4 o[4] = {};

  const int kstart = (q0 - WIN > 0) ? (q0 - WIN) : 0;
  const int kend = (q0 + 64 + WIN < NN) ? (q0 + 64 + WIN) : NN;
  const int nch = (kend - kstart) >> 6;
  const float scale = 0.125f;

  auto stage = [&](int bufi, int kc) {
#pragma unroll
    for (int j = 0; j < 2; ++j) {
      const int i = w * 2 + j;
      load_lds16(kbase + (((size_t)(kc + i * 8 + srow8)) << 6) + sswz,
                 &KV_lds[bufi][0][i * 512]);
      load_lds16(vbase + (((size_t)((kc >> 6) * 64 + i * 8 + srow8)) << 6) + sswz,
                 &KV_lds[bufi][1][i * 512]);
    }
  };

  stage(0, kstart);
  __syncthreads();

  for (int ic = 0; ic < nch; ++ic) {
    const int kc = kstart + ic * 64;
    const int bi = ic & 1;
    if (ic + 1 < nch) stage(bi ^ 1, kc + 64);

    const bf16_t* Kt = &KV_lds[bi][0][0];
    const bf16_t* Vt = &KV_lds[bi][1][0];

    f32x4 s[4];
#pragma unroll
    for (int t = 0; t < 4; ++t) {
      const bf16_t* kr = Kt + (t * 16 + lrow) * 64;
      bf16x8 kf0 = *reinterpret_cast<const bf16x8*>(kr + ((lkg ^ rs7) << 3));
      bf16x8 kf1 = *reinterpret_cast<const bf16x8*>(kr + (((4 + lkg) ^ rs7) << 3));
      f32x4 zz = {};
      zz = __builtin_amdgcn_mfma_f32_16x16x32_bf16(kf0, qf0, zz, 0, 0, 0);
      zz = __builtin_amdgcn_mfma_f32_16x16x32_bf16(kf1, qf1, zz, 0, 0, 0);
      s[t] = zz;
    }

    bf16x8 vf0[4], vf1[4];
#pragma unroll
    for (int f = 0; f < 4; ++f) {
      const bf16_t* vr = Vt + (f * 16 + lrow) * 64;
      vf0[f] = *reinterpret_cast<const bf16x8*>(vr + ((lkg ^ rs7) << 3));
      vf1[f] = *reinterpret_cast<const bf16x8*>(vr + (((4 + lkg) ^ rs7) << 3));
    }

    const bool needs_mask = (kc < qb - 113) || (kc > qb + 65);
    float p[4][4];
    float mloc = -1e30f, rsum = 0.f;
    if (needs_mask) {
      float v[4][4];
#pragma unroll
      for (int t = 0; t < 4; ++t)
#pragma unroll
        for (int r = 0; r < 4; ++r) {
          int k = kc + t * 16 + lkg * 4 + r;
          int d = qrow - k;
          bool ok = (unsigned)(d + WIN) <= 2u * WIN;
          v[t][r] = ok ? s[t][r] * scale : -1e30f;
          mloc = fmaxf(mloc, v[t][r]);
        }
      mloc = fmaxf(mloc, __shfl_xor(mloc, 16, 64));
      mloc = fmaxf(mloc, __shfl_xor(mloc, 32, 64));
      float mn = fmaxf(m_run, mloc);
      float corr = __expf(m_run - mn);
      m_run = mn;
#pragma unroll
      for (int t = 0; t < 4; ++t)
#pragma unroll
        for (int r = 0; r < 4; ++r) {
          int k = kc + t * 16 + lkg * 4 + r;
          int d = qrow - k;
          bool ok = (unsigned)(d + WIN) <= 2u * WIN;
          p[t][r] = ok ? __expf(v[t][r] - mn) : 0.f;
          rsum += p[t][r];
        }
      rsum += __shfl_xor(rsum, 16, 64);
      rsum += __shfl_xor(rsum, 32, 64);
      l_run = l_run * corr + rsum;
#pragma unroll
      for (int f = 0; f < 4; ++f) o[f] *= corr;
    } else {
      float v[4][4];
#pragma unroll
      for (int t = 0; t < 4; ++t)
#pragma unroll
        for (int r = 0; r < 4; ++r) {
          v[t][r] = s[t][r] * scale;
          mloc = fmaxf(mloc, v[t][r]);
        }
      mloc = fmaxf(mloc, __shfl_xor(mloc, 16, 64));
      mloc = fmaxf(mloc, __shfl_xor(mloc, 32, 64));
      float mn = fmaxf(m_run, mloc);
      float corr = __expf(m_run - mn);
      m_run = mn;
#pragma unroll
      for (int t = 0; t < 4; ++t)
#pragma unroll
        for (int r = 0; r < 4; ++r) {
          p[t][r] = __expf(v[t][r] - mn);
          rsum += p[t][r];
        }
      rsum += __shfl_xor(rsum, 16, 64);
      rsum += __shfl_xor(rsum, 32, 64);
      l_run = l_run * corr + rsum;
#pragma unroll
      for (int f = 0; f < 4; ++f) o[f] *= corr;
    }

    uint32_t* prow = &P_lds[w][lrow][0];
#pragma unroll
    for (int t = 0; t < 4; ++t)
#pragma unroll
      for (int c = 0; c < 2; ++c) {
        union { bf16_t hh[2]; uint32_t u; } pk;
        pk.hh[0] = (bf16_t)p[t][2 * c];
        pk.hh[1] = (bf16_t)p[t][2 * c + 1];
        int L = 8 * t + 2 * lkg + c;
        int pos = (((L >> 2) ^ rs7) << 2) | (L & 3);
        prow[pos] = pk.u;
      }
    asm volatile("" ::: "memory");
    const bf16_t* prd = reinterpret_cast<const bf16_t*>(&P_lds[w][lrow][0]);
    bf16x8 pa0 = *reinterpret_cast<const bf16x8*>(prd + ((lkg ^ rs7) << 3));
    bf16x8 pa1 = *reinterpret_cast<const bf16x8*>(prd + (((4 + lkg) ^ rs7) << 3));

#pragma unroll
    for (int f = 0; f < 4; ++f) {
      o[f] = __builtin_amdgcn_mfma_f32_16x16x32_bf16(vf0[f], pa0, o[f], 0, 0, 0);
      o[f] = __builtin_amdgcn_mfma_f32_16x16x32_bf16(vf1[f], pa1, o[f], 0, 0, 0);
    }
    __syncthreads();
  }

  float inv = 1.0f / l_run;
#pragma unroll
  for (int f = 0; f < 4; ++f) {
    union { bf16_t hh[4]; uint2 u; } ov;
#pragma unroll
    for (int r = 0; r < 4; ++r) ov.hh[r] = (bf16_t)(o[f][r] * inv);
    bf16_t* op = AO + (size_t)(b * NN + qrow) * ND + h * DHEAD + f * 16 + lkg * 4;
    *reinterpret_cast<uint2*>(op) = ov.u;
  }
}

extern "C" void kernel_launch(void* const* d_in, const int* in_sizes, int n_in,
                              void* d_out, int out_size, void* d_ws, size_t ws_size,
                              hipStream_t stream) {
  const float* x  = (const float*)d_in[0];
  const float* Wq = (const float*)d_in[1];
  const float* bq = (const float*)d_in[2];
  const float* Wk = (const float*)d_in[3];
  const float* bk = (const float*)d_in[4];
  const float* Wv = (const float*)d_in[5];
  const float* bv = (const float*)d_in[6];
  const float* Wo = (const float*)d_in[7];
  const float* bo = (const float*)d_in[8];
  float* out = (float*)d_out;

  bf16_t* ws  = (bf16_t*)d_ws;
  bf16_t* xb  = ws;
  bf16_t* Wqb = xb  + 4194304;
  bf16_t* Wkb = Wqb + 1048576;
  bf16_t* Wvb = Wkb + 1048576;
  bf16_t* Wob = Wvb + 1048576;
  bf16_t* Qh  = Wob + 1048576;
  bf16_t* Kh  = Qh  + 4194304;
  bf16_t* VTt = Kh  + 4194304;
  bf16_t* AOb = VTt + 4194304;

  cast_all<<<8192, 256, 0, stream>>>(x, Wq, Wk, Wv, Wo, xb, Wqb, Wkb, Wvb, Wob);

  qkv_gemm<<<dim3(8, 32, 3), 256, 0, stream>>>(xb, Wqb, Wkb, Wvb, bq, bk, bv, Qh, Kh, VTt);
  attn_kernel<<<1024, 256, 0, stream>>>(Qh, Kh, VTt, AOb);
  out_gemm2<<<dim3(8, 32), 512, 0, stream>>>(AOb, Wob, bo, out);
}